// Round 3
// baseline (467.007 us; speedup 1.0000x reference)
//
#include <hip/hip_runtime.h>
#include <stdint.h>

// B=2, SQ=SK=2048, HIDDEN=2048, HEADS=16, HEAD_DIM=128.
// DTYPE MODEL (verified): inputs fp32, mask int32, OUTPUT fp32. Internal bf16 MFMA.
// Round 11: same 256x256 BK=64 8-wave GEMM, K-loop restructured from the coarse
// 2-sync-per-tile split (measured: per-block MfmaUtil ~39%) to the verified m201
// fine interleave: 4 phases/K-tile, each {ds_reads; 2 glds; barrier; lgkmcnt(0);
// setprio; 16 MFMA; setprio; barrier}, vmcnt(4) folded into the closing barriers
// of ph2/ph4 (data boundaries for kk1/kk0-next). Ledger identical to round 10;
// only the barrier rhythm changes (m196: fine interleave is the lever).

#define LOG2E 1.44269504088896340736f
#define INV2PI 0.15915494309189535f

typedef __attribute__((ext_vector_type(8))) short bf16x8;
typedef __attribute__((ext_vector_type(8))) uint16_t u16x8;
typedef __attribute__((ext_vector_type(4))) uint16_t u16x4;
typedef __attribute__((ext_vector_type(4))) float f32x4;

__device__ __forceinline__ uint16_t f2bf(float f) {
  union { float f; uint32_t i; } v; v.f = f;
  uint32_t x = v.i;
  return (uint16_t)((x + 0x7fffu + ((x >> 16) & 1u)) >> 16);  // RTN-even
}
__device__ __forceinline__ uint32_t f_as_u(float f) { union { float f; uint32_t u; } v; v.f = f; return v.u; }
__device__ __forceinline__ float u_as_f(uint32_t u) { union { uint32_t u; float f; } v; v.u = u; return v.f; }
__device__ __forceinline__ void glds16(const void* g, void* l) {
  __builtin_amdgcn_global_load_lds((const __attribute__((address_space(1))) void*)g,
                                   (__attribute__((address_space(3))) void*)l, 16, 0, 0);
}

// fp32 -> bf16, 8 elems/thread, exact grid (n % 2048 == 0).
__global__ __launch_bounds__(256) void convert_f32_bf16(const float* __restrict__ in,
                                                        uint16_t* __restrict__ out) {
  const long i = ((long)blockIdx.x * 256 + threadIdx.x) * 8;
  const f32x4 a = *(const f32x4*)(in + i);
  const f32x4 b = *(const f32x4*)(in + i + 4);
  u16x8 o;
#pragma unroll
  for (int j = 0; j < 4; ++j) { o[j] = f2bf(a[j]); o[4 + j] = f2bf(b[j]); }
  *(u16x8*)(out + i) = o;
}

// All four weights -> one contiguous bf16 buffer W4 = [Wq|Wk|Wv|Wo], 4M elems each.
__global__ __launch_bounds__(256) void convert_w4(const float* __restrict__ Wq,
                                                  const float* __restrict__ Wk,
                                                  const float* __restrict__ Wv,
                                                  const float* __restrict__ Wo,
                                                  uint16_t* __restrict__ W4) {
  const int blk = blockIdx.x;        // 8192 blocks, 2048 per section
  const int sec = blk >> 11;
  const long off = ((long)(blk & 2047) * 256 + threadIdx.x) * 8;
  const float* src = (sec == 0) ? Wq : (sec == 1) ? Wk : (sec == 2) ? Wv : Wo;
  const f32x4 a = *(const f32x4*)(src + off);
  const f32x4 b = *(const f32x4*)(src + off + 4);
  u16x8 o;
#pragma unroll
  for (int j = 0; j < 4; ++j) { o[j] = f2bf(a[j]); o[4 + j] = f2bf(b[j]); }
  *(u16x8*)(W4 + (long)sec * 4194304 + off) = o;
}

// mask int -> additive softmax bias float (0 or -inf). 4096 elems.
__global__ __launch_bounds__(256) void mask_bias(const int* __restrict__ m,
                                                 float* __restrict__ bias) {
  const int i = blockIdx.x * 256 + threadIdx.x;
  bias[i] = m[i] ? 0.0f : -__builtin_inff();
}

// Epilogue modes
#define EPI_QKV 0  // N=6144: n<2048 RoPE*scale->Q; <4096 RoPE->K; else Vt
#define EPI_F32 1  // fp32 out (final projection)

// c is the section-local column; C has row stride 2048.
__device__ __forceinline__ void epi_rope_store(uint16_t* C, const f32x4& a, int rowbase,
                                               int c, float oscale) {
  const int f = (c >> 1) & 63;
  const float inv = __builtin_amdgcn_exp2f((float)f * (-13.287712379549449f / 64.0f));
  const float sgn = (c & 1) ? 1.0f : -1.0f;
#pragma unroll
  for (int r = 0; r < 4; ++r) {
    const float val = a[r];
    const float partner = __shfl_xor(val, 1);
    const int s = (rowbase + r) & 2047;
    const float rev = __builtin_amdgcn_fractf((float)s * inv * INV2PI);
    const float sn = __builtin_amdgcn_sinf(rev);
    const float cs = __builtin_amdgcn_cosf(rev);
    C[(long)(rowbase + r) * 2048 + c] = f2bf((val * cs + sgn * partner * sn) * oscale);
  }
}

// ---------------------------------------------------------------------------
// 256x256 tile, BK=64, 512 threads = 8 waves (2M x 4N), wave tile 128x64.
// C[m][n] = sum_k A[m][k] * W[n][k].  K-tile t lives in buffer t&1.
// m201 fine interleave: 4 phases/tile = (kk0,MH0)(kk0,MH1)(kk1,MH0)(kk1,MH1).
// Each phase: {ds_reads; 2 glds stage of tile t+1; barrier; lgkmcnt(0);
// setprio(1); 16 MFMA; setprio(0); closing barrier}.  vmcnt(4) before the
// closing barriers of ph2 (kk1 of tile t must land) and ph4 (kk0 of tile t+1).
// Per-wave ledger: 2 loads issued per phase, 8/tile; steady-state outstanding
// at each vm-sync = 8, retire oldest 4.  Never drains to 0 except tail.
//
// LDS element map (per operand, per buf, per kk): [256 rows][4 slots of 8]
// physical slot p at row r holds logical k-slot (p ^ ((r>>1)&3)).
// Staged: lane l of chunk ci covers row ci*16+(l>>2), phys slot l&3, so its
// GLOBAL source k-slot = (l&3) ^ ((row>>1)&3).  Read of logical slot `quad`:
// phys = quad ^ ((r16>>1)&3).  Same involution both sides (rule 21); row bases
// are multiples of 16 so the swizzle term is identical for every +16-row step.
// ---------------------------------------------------------------------------
template <int MODE>
__global__ __launch_bounds__(512, 2) void gemm256(const uint16_t* __restrict__ A0,
                                                  const uint16_t* __restrict__ A1,
                                                  const uint16_t* __restrict__ W,
                                                  void* __restrict__ C0v,
                                                  void* __restrict__ C1v,
                                                  void* __restrict__ C2v,
                                                  int M, int N, int K, float oscale) {
  __shared__ __align__(16) uint16_t As[2][2][8192];  // [buf][kk][256*32] = 64 KiB
  __shared__ __align__(16) uint16_t Bs[2][2][8192];  // 64 KiB
  const int tid = threadIdx.x;
  const int lane = tid & 63;
  const int w = tid >> 6;
  const int r16 = lane & 15, quad = lane >> 4;
  const int wm = w >> 2, wn = w & 3;

  // bijective XCD swizzle (nwg % 8 == 0), column-chunked: each XCD keeps its
  // W-panel L2-resident across all M-blocks.
  const int nby = M >> 8;
  const int nwg = gridDim.x;
  const int wg = ((int)blockIdx.x & 7) * (nwg >> 3) + ((int)blockIdx.x >> 3);
  const int by = wg % nby, bx = wg / nby;
  const int m0 = by << 8, n0 = bx << 8;

  const uint16_t* A = (MODE == EPI_QKV && n0 >= 2048) ? A1 : A0;

  // staging: wave w owns chunks 2w, 2w+1 (16 rows each) of every half-tile
  const int srow = 2 * w * 16 + (lane >> 2);           // rows srow, srow+16
  const int ssl = (lane & 3) ^ ((srow >> 1) & 3);      // same for srow+16
  const uint16_t* Ag0 = A + (long)(m0 + srow) * K + ssl * 8;
  const uint16_t* Ag1 = Ag0 + (long)16 * K;
  const uint16_t* Bg0 = W + (long)(n0 + srow) * K + ssl * 8;
  const uint16_t* Bg1 = Bg0 + (long)16 * K;
  const int ldso = w << 10;  // element offset of this wave's first 1 KiB chunk

  // fragment read offsets (elements within one [buf][kk] plane)
  const int sw = (r16 >> 1) & 3;
  const int aoff = (wm * 128 + r16) * 32 + ((quad ^ sw) << 3);
  const int boff = (wn * 64 + r16) * 32 + ((quad ^ sw) << 3);

  f32x4 acc[8][4] = {};
  bf16x8 af[4], bfr[4];

#define SCHED0() __builtin_amdgcn_sched_barrier(0)
#define G_STAGE_A(BUF, KK, T) do { \
    glds16(Ag0 + (long)(T) * 64 + (KK) * 32, &As[BUF][KK][ldso]); \
    glds16(Ag1 + (long)(T) * 64 + (KK) * 32, &As[BUF][KK][ldso + 512]); } while (0)
#define G_STAGE_B(BUF, KK, T) do { \
    glds16(Bg0 + (long)(T) * 64 + (KK) * 32, &Bs[BUF][KK][ldso]); \
    glds16(Bg1 + (long)(T) * 64 + (KK) * 32, &Bs[BUF][KK][ldso + 512]); } while (0)
#define LDS_B(BUF, KK) do { _Pragma("unroll") \
    for (int i = 0; i < 4; ++i) bfr[i] = *(const bf16x8*)&Bs[BUF][KK][boff + i * 512]; } while (0)
#define LDS_A(BUF, KK, MH) do { _Pragma("unroll") \
    for (int i = 0; i < 4; ++i) af[i] = *(const bf16x8*)&As[BUF][KK][aoff + ((MH) * 4 + i) * 512]; } while (0)
#define MFMA16(MH) do { __builtin_amdgcn_s_setprio(1); _Pragma("unroll") \
    for (int mi = 0; mi < 4; ++mi) { _Pragma("unroll") \
      for (int nt = 0; nt < 4; ++nt) \
        acc[(MH) * 4 + mi][nt] = __builtin_amdgcn_mfma_f32_16x16x32_bf16(af[mi], bfr[nt], acc[(MH) * 4 + mi][nt], 0, 0, 0); } \
    __builtin_amdgcn_s_setprio(0); } while (0)
// phase opener: all reads issued -> barrier -> wait own reads -> pinned MFMA
#define PH_MFMA(MH) do { SCHED0(); __builtin_amdgcn_s_barrier(); \
    asm volatile("s_waitcnt lgkmcnt(0)" ::: "memory"); SCHED0(); \
    MFMA16(MH); } while (0)
#define PH_END() do { SCHED0(); __builtin_amdgcn_s_barrier(); SCHED0(); } while (0)
#define PH_END_VM(NN) do { SCHED0(); \
    asm volatile("s_waitcnt vmcnt(" #NN ")" ::: "memory"); \
    __builtin_amdgcn_s_barrier(); SCHED0(); } while (0)

// one K-tile, staging tile T+1 into buffer BN.  bfr persists across MH pair.
#define TILE_MAIN(T, BC, BN) do { \
    LDS_B(BC, 0); LDS_A(BC, 0, 0); G_STAGE_A(BN, 0, (T) + 1); \
    PH_MFMA(0); PH_END(); \
    LDS_A(BC, 0, 1); G_STAGE_B(BN, 0, (T) + 1); \
    PH_MFMA(1); PH_END_VM(4); \
    LDS_B(BC, 1); LDS_A(BC, 1, 0); G_STAGE_A(BN, 1, (T) + 1); \
    PH_MFMA(0); PH_END(); \
    LDS_A(BC, 1, 1); G_STAGE_B(BN, 1, (T) + 1); \
    PH_MFMA(1); PH_END_VM(4); } while (0)

  // prologue: stage tile 0 (per-wave order Ak0,Bk0,Ak1,Bk1); land k0, keep k1.
  G_STAGE_A(0, 0, 0); G_STAGE_B(0, 0, 0); G_STAGE_A(0, 1, 0); G_STAGE_B(0, 1, 0);
  PH_END_VM(4);

  const int NT = K >> 6;  // 32 (even); tiles 0..NT-1
  int t = 0;
  for (; t < NT - 2; t += 2) { TILE_MAIN(t, 0, 1); TILE_MAIN(t + 1, 1, 0); }
  TILE_MAIN(t, 0, 1);  // t == NT-2 (even): stages tile NT-1 into buf 1

  // peeled tail tile NT-1 (buf 1): no staging; drain leftovers at mid-tile.
  LDS_B(1, 0); LDS_A(1, 0, 0); PH_MFMA(0); PH_END();
  LDS_A(1, 0, 1);              PH_MFMA(1); PH_END_VM(0);
  LDS_B(1, 1); LDS_A(1, 1, 0); PH_MFMA(0); PH_END();
  LDS_A(1, 1, 1);              PH_MFMA(1);

#undef SCHED0
#undef G_STAGE_A
#undef G_STAGE_B
#undef LDS_A
#undef LDS_B
#undef MFMA16
#undef PH_MFMA
#undef PH_END
#undef PH_END_VM
#undef TILE_MAIN

#pragma unroll
  for (int mt = 0; mt < 8; ++mt)
#pragma unroll
    for (int nt = 0; nt < 4; ++nt) {
      const int col = n0 + wn * 64 + nt * 16 + r16;
      const int rowbase = m0 + wm * 128 + mt * 16 + quad * 4;
      if constexpr (MODE == EPI_F32) {
        float* C = (float*)C0v;
#pragma unroll
        for (int r = 0; r < 4; ++r)
          C[(long)(rowbase + r) * N + col] = acc[mt][nt][r];
      } else {  // EPI_QKV: block-uniform branch on n0
        if (n0 < 2048) {
          epi_rope_store((uint16_t*)C0v, acc[mt][nt], rowbase, col, oscale);      // Q
        } else if (n0 < 4096) {
          epi_rope_store((uint16_t*)C1v, acc[mt][nt], rowbase, col - 2048, 1.0f); // K
        } else {
          uint16_t* Vt = (uint16_t*)C2v;
          const int c = col - 4096;
          const int h = c >> 7, d = c & 127;
          const int b = rowbase >> 11, s = rowbase & 2047;
          u16x4 pk;
#pragma unroll
          for (int r = 0; r < 4; ++r) pk[r] = f2bf(acc[mt][nt][r]);
          *(u16x4*)(Vt + (long)((b * 16 + h) * 128 + d) * 2048 + s) = pk;
        }
      }
    }
}

// Flash attention v4 (round-6, unchanged). Block = (b, h, 128 q) = 4 waves x 32 q.
// 32-key tiles, double-buffered staging, ONE barrier/iter, cross-barrier prefetch.
// LDS: Ks 2x8K + Vts 2x8K + Ps 4x2560 = 43008 B. Q arrives pre-scaled by scale*log2e.
__global__ __launch_bounds__(256) void attn_kernel(const uint16_t* __restrict__ Q,
                                                   const uint16_t* __restrict__ K,
                                                   const uint16_t* __restrict__ Vt,
                                                   const float* __restrict__ bias,
                                                   uint16_t* __restrict__ O) {
  __shared__ __align__(16) uint16_t Ks[2][32 * 128];   // [key][chunk16 ^ (key&7)]
  __shared__ __align__(16) uint16_t Vts[2][128 * 32];  // [dim][keychunk ^ (dim&3)]
  __shared__ __align__(16) uint16_t Ps[4][32 * 40];    // per-wave P, stride 40 (pad)
  const int tid = threadIdx.x;
  const int lane = tid & 63;
  const int w = tid >> 6;
  const int r16 = lane & 15, quad = lane >> 4;
  const int h = blockIdx.y, b = blockIdx.z;
  const int qbase = blockIdx.x * 128 + w * 32;

  bf16x8 qf[2][4];
#pragma unroll
  for (int t = 0; t < 2; ++t) {
    const uint16_t* qb = Q + ((long)(b * 2048 + qbase + t * 16 + r16)) * 2048 + h * 128 + quad * 8;
#pragma unroll
    for (int c = 0; c < 4; ++c) qf[t][c] = *(const bf16x8*)(qb + c * 32);
  }
  f32x4 oacc[2][8] = {};
  float li[2][4] = {};

  uint16_t* PsW = &Ps[w][0];
  const float* brow = bias + b * 2048;

  const int key0[2] = {8 * w + quad, 8 * w + 4 + quad};
  const uint16_t* kg[2];
  const uint16_t* vg[2];
#pragma unroll
  for (int i = 0; i < 2; ++i) {
    kg[i] = K + ((long)(b * 2048 + key0[i])) * 2048 + h * 128 + 8 * (r16 ^ ((4 * i + quad) & 7));
    const int dim = 32 * w + 16 * i + (lane >> 2);
    vg[i] = Vt + ((long)((b * 16 + h) * 128 + dim)) * 2048 + 8 * ((lane & 3) ^ ((lane >> 2) & 3));
  }

#pragma unroll
  for (int i = 0; i < 2; ++i) {
    glds16(kg[i], &Ks[0][(2 * w + i) * 512]);
    glds16(vg[i], &Vts[0][(2 * w + i) * 512]);
    kg[i] += 32 * 2048;
    vg[i] += 32;
  }
  float bn0 = brow[r16], bn1 = brow[16 + r16];

  auto body = [&](int k0, const uint16_t* Kc, const uint16_t* Vc,
                  uint16_t* Kn, uint16_t* Vn, bool pf) {
    __syncthreads();
    const float bc0 = bn0, bc1 = bn1;
    if (pf) {
#pragma unroll
      for (int i = 0; i < 2; ++i) {
        glds16(kg[i], Kn + (2 * w + i) * 512);
        glds16(vg[i], Vn + (2 * w + i) * 512);
        kg[i] += 32 * 2048;
        vg[i] += 32;
      }
      bn0 = brow[k0 + 32 + r16];
      bn1 = brow[k0 + 48 + r16];
    }
#pragma unroll
    for (int ct = 0; ct < 2; ++ct) {
      const int key = ct * 16 + r16;
      const int kb = key & 7;
      bf16x8 kf[4];
#pragma unroll
      for (int c = 0; c < 4; ++c)
        kf[c] = *(const bf16x8*)(Kc + key * 128 + ((4 * c + quad) ^ kb) * 8);
      const float bv = ct ? bc1 : bc0;
      const int pc = ct * 2 + (r16 >> 3);
#pragma unroll
      for (int t = 0; t < 2; ++t) {
        f32x4 s = {};
#pragma unroll
        for (int c = 0; c < 4; ++c)
          s = __builtin_amdgcn_mfma_f32_16x16x32_bf16(qf[t][c], kf[c], s, 0, 0, 0);
#pragma unroll
        for (int r = 0; r < 4; ++r) {
          const float p = __builtin_amdgcn_exp2f(s[r] + bv);
          const uint32_t pb = f_as_u(p) + 0x8000u;  // round-half-up to bf16
          const int row = t * 16 + quad * 4 + r;    // row&3 == r
          PsW[row * 40 + ((pc ^ r) << 3) + (r16 & 7)] = (uint16_t)(pb >> 16);
          li[t][r] += u_as_f(pb & 0xffff0000u);
        }
      }
    }
    bf16x8 pa[2];
#pragma unroll
    for (int t = 0; t < 2; ++t)
      pa[t] = *(const bf16x8*)(PsW + (t * 16 + r16) * 40 + ((quad ^ (r16 & 3)) << 3));
#pragma unroll
    for (int nt = 0; nt < 8; ++nt) {
      const int dim = nt * 16 + r16;
      bf16x8 vf = *(const bf16x8*)(Vc + dim * 32 + ((quad ^ (dim & 3)) << 3));
#pragma unroll
      for (int t = 0; t < 2; ++t)
        oacc[t][nt] = __builtin_amdgcn_mfma_f32_16x16x32_bf16(pa[t], vf, oacc[t][nt], 0, 0, 0);
    }
  };

  for (int kt2 = 0; kt2 < 32; ++kt2) {
    body(64 * kt2,      &Ks[0][0], &Vts[0][0], &Ks[1][0], &Vts[1][0], true);
    body(64 * kt2 + 32, &Ks[1][0], &Vts[1][0], &Ks[0][0], &Vts[0][0], kt2 < 31);
  }

#pragma unroll
  for (int off = 1; off < 16; off <<= 1)
#pragma unroll
    for (int t = 0; t < 2; ++t)
#pragma unroll
      for (int r = 0; r < 4; ++r) li[t][r] += __shfl_xor(li[t][r], off);

#pragma unroll
  for (int t = 0; t < 2; ++t) {
    uint16_t* ob = O + ((long)(b * 2048 + qbase + t * 16)) * 2048 + h * 128;
    float inv_l[4];
#pragma unroll
    for (int r = 0; r < 4; ++r) inv_l[r] = 1.0f / li[t][r];
#pragma unroll
    for (int nt = 0; nt < 8; ++nt)
#pragma unroll
      for (int r = 0; r < 4; ++r)
        ob[(long)(quad * 4 + r) * 2048 + nt * 16 + r16] = f2bf(oacc[t][nt][r] * inv_l[r]);
  }
}

extern "C" void kernel_launch(void* const* d_in, const int* in_sizes, int n_in,
                              void* d_out, int out_size, void* d_ws, size_t ws_size,
                              hipStream_t stream) {
  const float* x   = (const float*)d_in[0];
  const float* enc = (const float*)d_in[1];
  const int*   msk = (const int*)d_in[2];
  const float* Wq  = (const float*)d_in[3];
  const float* Wk  = (const float*)d_in[4];
  const float* Wv  = (const float*)d_in[5];
  const float* Wo  = (const float*)d_in[6];
  float* out = (float*)d_out;

  const long NELT = 8L * 1024 * 1024;  // 4096 x 2048 elems
  const long WELT = 4L * 1024 * 1024;  // 2048 x 2048 elems
  // d_ws (80 MiB + 16 KiB used): Qb[8M] Kb[8M] Vtb[8M] W4[16M] | bias
  uint16_t* Qb  = (uint16_t*)d_ws;
  uint16_t* Kb  = Qb + NELT;
  uint16_t* Vtb = Kb + NELT;
  uint16_t* W4  = Vtb + NELT;
  float* biasb  = (float*)(W4 + 4 * WELT);
  // d_out doubles as scratch for bf16 activations until the final GEMM overwrites it.
  uint16_t* xb   = (uint16_t*)d_out;        // 8M elems = 16 MB
  uint16_t* encb = xb + NELT;               // 8M elems = 16 MB (total 32 MB = out size)
  uint16_t* Ob   = W4;                      // Wq/Wk region dead after QKV GEMM

  const float cs_exp = 0.088388347648318447f * LOG2E;  // folded into Q

  convert_f32_bf16<<<(int)(NELT / 2048), 256, 0, stream>>>(x, xb);
  convert_f32_bf16<<<(int)(NELT / 2048), 256, 0, stream>>>(enc, encb);
  convert_w4<<<8192, 256, 0, stream>>>(Wq, Wk, Wv, Wo, W4);
  mask_bias<<<16, 256, 0, stream>>>(msk, biasb);

  // QKV mega-GEMM: 256^2 tiles, grid 16x24 = 384 blocks (384 % 8 == 0)
  gemm256<EPI_QKV><<<384, 512, 0, stream>>>(xb, encb, W4, Qb, Kb, Vtb,
                                            4096, 6144, 2048, cs_exp);

  attn_kernel<<<dim3(16, 16, 2), 256, 0, stream>>>(Qb, Kb, Vtb, biasb, Ob);

  // Final projection: 16x8 = 128 blocks; A = Ob (aliases dead Wq/Wk), W = Wo
  gemm256<EPI_F32><<<128, 512, 0, stream>>>(Ob, nullptr, W4 + 3 * WELT,
                                            out, nullptr, nullptr,
                                            4096, 2048, 2048, 1.0f);
}

// Round 4
// 445.995 us; speedup vs baseline: 1.0471x; 1.0471x over previous
//
#include <hip/hip_runtime.h>
#include <stdint.h>

// B=2, SQ=SK=2048, HIDDEN=2048, HEADS=16, HEAD_DIM=128.
// DTYPE MODEL (verified): inputs fp32, mask int32, OUTPUT fp32. Internal bf16 MFMA.
// Round 12: revert QKV K-loop to the measured round-10 structure (146 us, 706 TF:
// 256x256 BK=64, 2 counted-vmcnt syncs per K-tile -- the fine 8-barrier interleave
// of round 11 regressed to 198 us; fixed per-sync overhead F ~ 1.6x the 32-MFMA
// slab dominates at 1 block/CU).  New: final projection retiled to BM=128 BN=256
// (separate kernel gemm_proj, grid 32x8 = 256 blocks = ONE full round on 256 CUs
// vs the old 128-block half-idle grid).  Same verified ledger at vmcnt(3).

#define LOG2E 1.44269504088896340736f
#define INV2PI 0.15915494309189535f

typedef __attribute__((ext_vector_type(8))) short bf16x8;
typedef __attribute__((ext_vector_type(8))) uint16_t u16x8;
typedef __attribute__((ext_vector_type(4))) uint16_t u16x4;
typedef __attribute__((ext_vector_type(4))) float f32x4;

__device__ __forceinline__ uint16_t f2bf(float f) {
  union { float f; uint32_t i; } v; v.f = f;
  uint32_t x = v.i;
  return (uint16_t)((x + 0x7fffu + ((x >> 16) & 1u)) >> 16);  // RTN-even
}
__device__ __forceinline__ uint32_t f_as_u(float f) { union { float f; uint32_t u; } v; v.f = f; return v.u; }
__device__ __forceinline__ float u_as_f(uint32_t u) { union { uint32_t u; float f; } v; v.u = u; return v.f; }
__device__ __forceinline__ void glds16(const void* g, void* l) {
  __builtin_amdgcn_global_load_lds((const __attribute__((address_space(1))) void*)g,
                                   (__attribute__((address_space(3))) void*)l, 16, 0, 0);
}

// fp32 -> bf16, 8 elems/thread, exact grid (n % 2048 == 0).
__global__ __launch_bounds__(256) void convert_f32_bf16(const float* __restrict__ in,
                                                        uint16_t* __restrict__ out) {
  const long i = ((long)blockIdx.x * 256 + threadIdx.x) * 8;
  const f32x4 a = *(const f32x4*)(in + i);
  const f32x4 b = *(const f32x4*)(in + i + 4);
  u16x8 o;
#pragma unroll
  for (int j = 0; j < 4; ++j) { o[j] = f2bf(a[j]); o[4 + j] = f2bf(b[j]); }
  *(u16x8*)(out + i) = o;
}

// All four weights -> one contiguous bf16 buffer W4 = [Wq|Wk|Wv|Wo], 4M elems each.
__global__ __launch_bounds__(256) void convert_w4(const float* __restrict__ Wq,
                                                  const float* __restrict__ Wk,
                                                  const float* __restrict__ Wv,
                                                  const float* __restrict__ Wo,
                                                  uint16_t* __restrict__ W4) {
  const int blk = blockIdx.x;        // 8192 blocks, 2048 per section
  const int sec = blk >> 11;
  const long off = ((long)(blk & 2047) * 256 + threadIdx.x) * 8;
  const float* src = (sec == 0) ? Wq : (sec == 1) ? Wk : (sec == 2) ? Wv : Wo;
  const f32x4 a = *(const f32x4*)(src + off);
  const f32x4 b = *(const f32x4*)(src + off + 4);
  u16x8 o;
#pragma unroll
  for (int j = 0; j < 4; ++j) { o[j] = f2bf(a[j]); o[4 + j] = f2bf(b[j]); }
  *(u16x8*)(W4 + (long)sec * 4194304 + off) = o;
}

// mask int -> additive softmax bias float (0 or -inf). 4096 elems.
__global__ __launch_bounds__(256) void mask_bias(const int* __restrict__ m,
                                                 float* __restrict__ bias) {
  const int i = blockIdx.x * 256 + threadIdx.x;
  bias[i] = m[i] ? 0.0f : -__builtin_inff();
}

// c is the section-local column; C has row stride 2048.
__device__ __forceinline__ void epi_rope_store(uint16_t* C, const f32x4& a, int rowbase,
                                               int c, float oscale) {
  const int f = (c >> 1) & 63;
  const float inv = __builtin_amdgcn_exp2f((float)f * (-13.287712379549449f / 64.0f));
  const float sgn = (c & 1) ? 1.0f : -1.0f;
#pragma unroll
  for (int r = 0; r < 4; ++r) {
    const float val = a[r];
    const float partner = __shfl_xor(val, 1);
    const int s = (rowbase + r) & 2047;
    const float rev = __builtin_amdgcn_fractf((float)s * inv * INV2PI);
    const float sn = __builtin_amdgcn_sinf(rev);
    const float cs = __builtin_amdgcn_cosf(rev);
    C[(long)(rowbase + r) * 2048 + c] = f2bf((val * cs + sgn * partner * sn) * oscale);
  }
}

// ---------------------------------------------------------------------------
// QKV mega-GEMM: 256x256 tile, BK=64, 512 threads = 8 waves (2M x 4N).
// Round-10 verified structure (146 us): 2 counted-vmcnt syncs per K-tile,
// phases = (kk0: stageA,dsB,dsA0,MFMA,stageB,dsA1,MFMA | VMBAR4) x2.
// LDS map: [256 rows][4 slots of 8]; phys slot p at row r holds logical
// k-slot p ^ ((r>>1)&3); staged via pre-swizzled global source (rule 21).
// ---------------------------------------------------------------------------
__global__ __launch_bounds__(512, 2) void gemm256(const uint16_t* __restrict__ A0,
                                                  const uint16_t* __restrict__ A1,
                                                  const uint16_t* __restrict__ W,
                                                  uint16_t* __restrict__ Qb,
                                                  uint16_t* __restrict__ Kb,
                                                  uint16_t* __restrict__ Vtb,
                                                  int M, int N, int K, float oscale) {
  __shared__ __align__(16) uint16_t As[2][2][8192];  // [buf][kk][256*32] = 64 KiB
  __shared__ __align__(16) uint16_t Bs[2][2][8192];  // 64 KiB
  const int tid = threadIdx.x;
  const int lane = tid & 63;
  const int w = tid >> 6;
  const int r16 = lane & 15, quad = lane >> 4;
  const int wm = w >> 2, wn = w & 3;

  // bijective XCD swizzle (nwg % 8 == 0), column-chunked.
  const int nby = M >> 8;
  const int nwg = gridDim.x;
  const int wg = ((int)blockIdx.x & 7) * (nwg >> 3) + ((int)blockIdx.x >> 3);
  const int by = wg % nby, bx = wg / nby;
  const int m0 = by << 8, n0 = bx << 8;

  const uint16_t* A = (n0 >= 2048) ? A1 : A0;

  // staging: wave w owns chunks 2w, 2w+1 (16 rows each) of every half-tile
  const int srow = 2 * w * 16 + (lane >> 2);           // rows srow, srow+16
  const int ssl = (lane & 3) ^ ((srow >> 1) & 3);      // same for srow+16
  const uint16_t* Ag0 = A + (long)(m0 + srow) * K + ssl * 8;
  const uint16_t* Ag1 = Ag0 + (long)16 * K;
  const uint16_t* Bg0 = W + (long)(n0 + srow) * K + ssl * 8;
  const uint16_t* Bg1 = Bg0 + (long)16 * K;
  const int ldso = w << 10;  // element offset of this wave's first 1 KiB chunk

  // fragment read offsets (elements within one [buf][kk] plane)
  const int sw = (r16 >> 1) & 3;
  const int aoff = (wm * 128 + r16) * 32 + ((quad ^ sw) << 3);
  const int boff = (wn * 64 + r16) * 32 + ((quad ^ sw) << 3);

  f32x4 acc[8][4] = {};
  bf16x8 af[4], bfr[4];

#define SCHED0() __builtin_amdgcn_sched_barrier(0)
#define G_STAGE_A(BUF, KK, T) do { \
    glds16(Ag0 + (long)(T) * 64 + (KK) * 32, &As[BUF][KK][ldso]); \
    glds16(Ag1 + (long)(T) * 64 + (KK) * 32, &As[BUF][KK][ldso + 512]); } while (0)
#define G_STAGE_B(BUF, KK, T) do { \
    glds16(Bg0 + (long)(T) * 64 + (KK) * 32, &Bs[BUF][KK][ldso]); \
    glds16(Bg1 + (long)(T) * 64 + (KK) * 32, &Bs[BUF][KK][ldso + 512]); } while (0)
#define LDS_B(BUF, KK) do { _Pragma("unroll") \
    for (int i = 0; i < 4; ++i) bfr[i] = *(const bf16x8*)&Bs[BUF][KK][boff + i * 512]; } while (0)
#define LDS_A(BUF, KK, MH) do { _Pragma("unroll") \
    for (int i = 0; i < 4; ++i) af[i] = *(const bf16x8*)&As[BUF][KK][aoff + ((MH) * 4 + i) * 512]; } while (0)
#define MFMA16(MH) do { __builtin_amdgcn_s_setprio(1); _Pragma("unroll") \
    for (int mi = 0; mi < 4; ++mi) { _Pragma("unroll") \
      for (int nt = 0; nt < 4; ++nt) \
        acc[(MH) * 4 + mi][nt] = __builtin_amdgcn_mfma_f32_16x16x32_bf16(af[mi], bfr[nt], acc[(MH) * 4 + mi][nt], 0, 0, 0); } \
    __builtin_amdgcn_s_setprio(0); } while (0)
#define VMBAR(NN) do { SCHED0(); \
    asm volatile("s_waitcnt vmcnt(" #NN ")" ::: "memory"); \
    __builtin_amdgcn_s_barrier(); \
    SCHED0(); } while (0)
#define TILE_ITER(T, BC, BN) do { \
    G_STAGE_A(BN, 0, (T) + 1); LDS_B(BC, 0); LDS_A(BC, 0, 0); MFMA16(0); \
    G_STAGE_B(BN, 0, (T) + 1); LDS_A(BC, 0, 1); MFMA16(1); \
    VMBAR(4); \
    G_STAGE_A(BN, 1, (T) + 1); LDS_B(BC, 1); LDS_A(BC, 1, 0); MFMA16(0); \
    G_STAGE_B(BN, 1, (T) + 1); LDS_A(BC, 1, 1); MFMA16(1); \
    VMBAR(4); } while (0)

  // prologue: stage tile 0 fully; land k0 halves, keep k1 halves in flight
  G_STAGE_A(0, 0, 0); G_STAGE_B(0, 0, 0); G_STAGE_A(0, 1, 0); G_STAGE_B(0, 1, 0);
  VMBAR(4);

  const int NT = K >> 6;  // 32 (even); tiles 0..NT-1
  int t = 0;
  for (; t + 2 < NT; t += 2) { TILE_ITER(t, 0, 1); TILE_ITER(t + 1, 1, 0); }
  TILE_ITER(t, 0, 1);  // t == NT-2 (even): stages tile NT-1 into buf 1

  // peeled tail tile NT-1 (buf 1): no staging; drain its k1 at mid-tile
  LDS_B(1, 0); LDS_A(1, 0, 0); MFMA16(0);
  LDS_A(1, 0, 1); MFMA16(1);
  VMBAR(0);
  LDS_B(1, 1); LDS_A(1, 1, 0); MFMA16(0);
  LDS_A(1, 1, 1); MFMA16(1);

#undef G_STAGE_A
#undef G_STAGE_B
#undef LDS_A
#undef LDS_B
#undef TILE_ITER

#pragma unroll
  for (int mt = 0; mt < 8; ++mt)
#pragma unroll
    for (int nt = 0; nt < 4; ++nt) {
      const int col = n0 + wn * 64 + nt * 16 + r16;
      const int rowbase = m0 + wm * 128 + mt * 16 + quad * 4;
      if (n0 < 2048) {
        epi_rope_store(Qb, acc[mt][nt], rowbase, col, oscale);       // Q
      } else if (n0 < 4096) {
        epi_rope_store(Kb, acc[mt][nt], rowbase, col - 2048, 1.0f);  // K
      } else {
        const int c = col - 4096;
        const int h = c >> 7, d = c & 127;
        const int b = rowbase >> 11, s = rowbase & 2047;
        u16x4 pk;
#pragma unroll
        for (int r = 0; r < 4; ++r) pk[r] = f2bf(acc[mt][nt][r]);
        *(u16x4*)(Vtb + (long)((b * 16 + h) * 128 + d) * 2048 + s) = pk;
      }
    }
}

// ---------------------------------------------------------------------------
// Final projection: BM=128, BN=256, BK=64, 8 waves (2M x 4N) -> wave 64x64.
// Grid 32x8 = 256 blocks = one full round on 256 CUs (old: 128 blocks, half
// idle).  Same ledger as gemm256 with L=3 loads/half-tile -> vmcnt(3).
// LDS: As 2x2x[128x32]=32K + Bs 2x2x[256x32]=64K = 96 KiB.
// ---------------------------------------------------------------------------
__global__ __launch_bounds__(512, 2) void gemm_proj(const uint16_t* __restrict__ A0,
                                                    const uint16_t* __restrict__ W,
                                                    float* __restrict__ C,
                                                    int M, int N, int K) {
  __shared__ __align__(16) uint16_t As[2][2][4096];  // [buf][kk][128*32] = 32 KiB
  __shared__ __align__(16) uint16_t Bs[2][2][8192];  // [buf][kk][256*32] = 64 KiB
  const int tid = threadIdx.x;
  const int lane = tid & 63;
  const int w = tid >> 6;
  const int r16 = lane & 15, quad = lane >> 4;
  const int wm = w >> 2, wn = w & 3;

  const int nby = M >> 7;  // BM=128
  const int nwg = gridDim.x;
  const int wg = ((int)blockIdx.x & 7) * (nwg >> 3) + ((int)blockIdx.x >> 3);
  const int by = wg % nby, bx = wg / nby;
  const int m0 = by << 7, n0 = bx << 8;

  // staging: wave w owns A chunk w (16 rows) and B chunks 2w, 2w+1
  const int sa_row = 16 * w + (lane >> 2);
  const int sb_row = 32 * w + (lane >> 2);
  const int ssl = (lane & 3) ^ (((lane >> 2) >> 1) & 3);
  const uint16_t* Ag = A0 + (long)(m0 + sa_row) * K + ssl * 8;
  const uint16_t* Bg0 = W + (long)(n0 + sb_row) * K + ssl * 8;
  const uint16_t* Bg1 = Bg0 + (long)16 * K;

  const int sw = (r16 >> 1) & 3;
  const int aoff = (wm * 64 + r16) * 32 + ((quad ^ sw) << 3);
  const int boff = (wn * 64 + r16) * 32 + ((quad ^ sw) << 3);

  f32x4 acc[4][4] = {};
  bf16x8 af[4], bfr[4];

#define PG_STAGE_A(BUF, KK, T) \
    glds16(Ag + (long)(T) * 64 + (KK) * 32, &As[BUF][KK][w * 512])
#define PG_STAGE_B(BUF, KK, T) do { \
    glds16(Bg0 + (long)(T) * 64 + (KK) * 32, &Bs[BUF][KK][2 * w * 512]); \
    glds16(Bg1 + (long)(T) * 64 + (KK) * 32, &Bs[BUF][KK][2 * w * 512 + 512]); } while (0)
#define PLDS_B(BUF, KK) do { _Pragma("unroll") \
    for (int i = 0; i < 4; ++i) bfr[i] = *(const bf16x8*)&Bs[BUF][KK][boff + i * 512]; } while (0)
#define PLDS_A(BUF, KK) do { _Pragma("unroll") \
    for (int i = 0; i < 4; ++i) af[i] = *(const bf16x8*)&As[BUF][KK][aoff + i * 512]; } while (0)
#define PMFMA(MT0, MT1) do { __builtin_amdgcn_s_setprio(1); _Pragma("unroll") \
    for (int mi = (MT0); mi < (MT1); ++mi) { _Pragma("unroll") \
      for (int nt = 0; nt < 4; ++nt) \
        acc[mi][nt] = __builtin_amdgcn_mfma_f32_16x16x32_bf16(af[mi], bfr[nt], acc[mi][nt], 0, 0, 0); } \
    __builtin_amdgcn_s_setprio(0); } while (0)
#define PTILE(T, BC, BN) do { \
    PG_STAGE_A(BN, 0, (T) + 1); PLDS_B(BC, 0); PLDS_A(BC, 0); PMFMA(0, 2); \
    PG_STAGE_B(BN, 0, (T) + 1); PMFMA(2, 4); \
    VMBAR(3); \
    PG_STAGE_A(BN, 1, (T) + 1); PLDS_B(BC, 1); PLDS_A(BC, 1); PMFMA(0, 2); \
    PG_STAGE_B(BN, 1, (T) + 1); PMFMA(2, 4); \
    VMBAR(3); } while (0)

  PG_STAGE_A(0, 0, 0); PG_STAGE_B(0, 0, 0); PG_STAGE_A(0, 1, 0); PG_STAGE_B(0, 1, 0);
  VMBAR(3);

  const int NT = K >> 6;  // 32
  int t = 0;
  for (; t + 2 < NT; t += 2) { PTILE(t, 0, 1); PTILE(t + 1, 1, 0); }
  PTILE(t, 0, 1);

  PLDS_B(1, 0); PLDS_A(1, 0); PMFMA(0, 4);
  VMBAR(0);
  PLDS_B(1, 1); PLDS_A(1, 1); PMFMA(0, 4);

#undef PG_STAGE_A
#undef PG_STAGE_B
#undef PLDS_A
#undef PLDS_B
#undef PMFMA
#undef PTILE
#undef MFMA16
#undef VMBAR
#undef SCHED0

#pragma unroll
  for (int mt = 0; mt < 4; ++mt)
#pragma unroll
    for (int nt = 0; nt < 4; ++nt) {
      const int col = n0 + wn * 64 + nt * 16 + r16;
      const int rowbase = m0 + wm * 64 + mt * 16 + quad * 4;
#pragma unroll
      for (int r = 0; r < 4; ++r)
        C[(long)(rowbase + r) * N + col] = acc[mt][nt][r];
    }
}

// Flash attention v4 (round-6, unchanged). Block = (b, h, 128 q) = 4 waves x 32 q.
// 32-key tiles, double-buffered staging, ONE barrier/iter, cross-barrier prefetch.
// LDS: Ks 2x8K + Vts 2x8K + Ps 4x2560 = 43008 B. Q arrives pre-scaled by scale*log2e.
__global__ __launch_bounds__(256) void attn_kernel(const uint16_t* __restrict__ Q,
                                                   const uint16_t* __restrict__ K,
                                                   const uint16_t* __restrict__ Vt,
                                                   const float* __restrict__ bias,
                                                   uint16_t* __restrict__ O) {
  __shared__ __align__(16) uint16_t Ks[2][32 * 128];   // [key][chunk16 ^ (key&7)]
  __shared__ __align__(16) uint16_t Vts[2][128 * 32];  // [dim][keychunk ^ (dim&3)]
  __shared__ __align__(16) uint16_t Ps[4][32 * 40];    // per-wave P, stride 40 (pad)
  const int tid = threadIdx.x;
  const int lane = tid & 63;
  const int w = tid >> 6;
  const int r16 = lane & 15, quad = lane >> 4;
  const int h = blockIdx.y, b = blockIdx.z;
  const int qbase = blockIdx.x * 128 + w * 32;

  bf16x8 qf[2][4];
#pragma unroll
  for (int t = 0; t < 2; ++t) {
    const uint16_t* qb = Q + ((long)(b * 2048 + qbase + t * 16 + r16)) * 2048 + h * 128 + quad * 8;
#pragma unroll
    for (int c = 0; c < 4; ++c) qf[t][c] = *(const bf16x8*)(qb + c * 32);
  }
  f32x4 oacc[2][8] = {};
  float li[2][4] = {};

  uint16_t* PsW = &Ps[w][0];
  const float* brow = bias + b * 2048;

  const int key0[2] = {8 * w + quad, 8 * w + 4 + quad};
  const uint16_t* kg[2];
  const uint16_t* vg[2];
#pragma unroll
  for (int i = 0; i < 2; ++i) {
    kg[i] = K + ((long)(b * 2048 + key0[i])) * 2048 + h * 128 + 8 * (r16 ^ ((4 * i + quad) & 7));
    const int dim = 32 * w + 16 * i + (lane >> 2);
    vg[i] = Vt + ((long)((b * 16 + h) * 128 + dim)) * 2048 + 8 * ((lane & 3) ^ ((lane >> 2) & 3));
  }

#pragma unroll
  for (int i = 0; i < 2; ++i) {
    glds16(kg[i], &Ks[0][(2 * w + i) * 512]);
    glds16(vg[i], &Vts[0][(2 * w + i) * 512]);
    kg[i] += 32 * 2048;
    vg[i] += 32;
  }
  float bn0 = brow[r16], bn1 = brow[16 + r16];

  auto body = [&](int k0, const uint16_t* Kc, const uint16_t* Vc,
                  uint16_t* Kn, uint16_t* Vn, bool pf) {
    __syncthreads();
    const float bc0 = bn0, bc1 = bn1;
    if (pf) {
#pragma unroll
      for (int i = 0; i < 2; ++i) {
        glds16(kg[i], Kn + (2 * w + i) * 512);
        glds16(vg[i], Vn + (2 * w + i) * 512);
        kg[i] += 32 * 2048;
        vg[i] += 32;
      }
      bn0 = brow[k0 + 32 + r16];
      bn1 = brow[k0 + 48 + r16];
    }
#pragma unroll
    for (int ct = 0; ct < 2; ++ct) {
      const int key = ct * 16 + r16;
      const int kb = key & 7;
      bf16x8 kf[4];
#pragma unroll
      for (int c = 0; c < 4; ++c)
        kf[c] = *(const bf16x8*)(Kc + key * 128 + ((4 * c + quad) ^ kb) * 8);
      const float bv = ct ? bc1 : bc0;
      const int pc = ct * 2 + (r16 >> 3);
#pragma unroll
      for (int t = 0; t < 2; ++t) {
        f32x4 s = {};
#pragma unroll
        for (int c = 0; c < 4; ++c)
          s = __builtin_amdgcn_mfma_f32_16x16x32_bf16(qf[t][c], kf[c], s, 0, 0, 0);
#pragma unroll
        for (int r = 0; r < 4; ++r) {
          const float p = __builtin_amdgcn_exp2f(s[r] + bv);
          const uint32_t pb = f_as_u(p) + 0x8000u;  // round-half-up to bf16
          const int row = t * 16 + quad * 4 + r;    // row&3 == r
          PsW[row * 40 + ((pc ^ r) << 3) + (r16 & 7)] = (uint16_t)(pb >> 16);
          li[t][r] += u_as_f(pb & 0xffff0000u);
        }
      }
    }
    bf16x8 pa[2];
#pragma unroll
    for (int t = 0; t < 2; ++t)
      pa[t] = *(const bf16x8*)(PsW + (t * 16 + r16) * 40 + ((quad ^ (r16 & 3)) << 3));
#pragma unroll
    for (int nt = 0; nt < 8; ++nt) {
      const int dim = nt * 16 + r16;
      bf16x8 vf = *(const bf16x8*)(Vc + dim * 32 + ((quad ^ (dim & 3)) << 3));
#pragma unroll
      for (int t = 0; t < 2; ++t)
        oacc[t][nt] = __builtin_amdgcn_mfma_f32_16x16x32_bf16(pa[t], vf, oacc[t][nt], 0, 0, 0);
    }
  };

  for (int kt2 = 0; kt2 < 32; ++kt2) {
    body(64 * kt2,      &Ks[0][0], &Vts[0][0], &Ks[1][0], &Vts[1][0], true);
    body(64 * kt2 + 32, &Ks[1][0], &Vts[1][0], &Ks[0][0], &Vts[0][0], kt2 < 31);
  }

#pragma unroll
  for (int off = 1; off < 16; off <<= 1)
#pragma unroll
    for (int t = 0; t < 2; ++t)
#pragma unroll
      for (int r = 0; r < 4; ++r) li[t][r] += __shfl_xor(li[t][r], off);

#pragma unroll
  for (int t = 0; t < 2; ++t) {
    uint16_t* ob = O + ((long)(b * 2048 + qbase + t * 16)) * 2048 + h * 128;
    float inv_l[4];
#pragma unroll
    for (int r = 0; r < 4; ++r) inv_l[r] = 1.0f / li[t][r];
#pragma unroll
    for (int nt = 0; nt < 8; ++nt)
#pragma unroll
      for (int r = 0; r < 4; ++r)
        ob[(long)(quad * 4 + r) * 2048 + nt * 16 + r16] = f2bf(oacc[t][nt][r] * inv_l[r]);
  }
}

extern "C" void kernel_launch(void* const* d_in, const int* in_sizes, int n_in,
                              void* d_out, int out_size, void* d_ws, size_t ws_size,
                              hipStream_t stream) {
  const float* x   = (const float*)d_in[0];
  const float* enc = (const float*)d_in[1];
  const int*   msk = (const int*)d_in[2];
  const float* Wq  = (const float*)d_in[3];
  const float* Wk  = (const float*)d_in[4];
  const float* Wv  = (const float*)d_in[5];
  const float* Wo  = (const float*)d_in[6];
  float* out = (float*)d_out;

  const long NELT = 8L * 1024 * 1024;  // 4096 x 2048 elems
  const long WELT = 4L * 1024 * 1024;  // 2048 x 2048 elems
  // d_ws (80 MiB + 16 KiB used): Qb[8M] Kb[8M] Vtb[8M] W4[16M] | bias
  uint16_t* Qb  = (uint16_t*)d_ws;
  uint16_t* Kb  = Qb + NELT;
  uint16_t* Vtb = Kb + NELT;
  uint16_t* W4  = Vtb + NELT;
  float* biasb  = (float*)(W4 + 4 * WELT);
  // d_out doubles as scratch for bf16 activations until the final GEMM overwrites it.
  uint16_t* xb   = (uint16_t*)d_out;        // 8M elems = 16 MB
  uint16_t* encb = xb + NELT;               // 8M elems = 16 MB (total 32 MB = out size)
  uint16_t* Ob   = W4;                      // Wq/Wk region dead after QKV GEMM

  const float cs_exp = 0.088388347648318447f * LOG2E;  // folded into Q

  convert_f32_bf16<<<(int)(NELT / 2048), 256, 0, stream>>>(x, xb);
  convert_f32_bf16<<<(int)(NELT / 2048), 256, 0, stream>>>(enc, encb);
  convert_w4<<<8192, 256, 0, stream>>>(Wq, Wk, Wv, Wo, W4);
  mask_bias<<<16, 256, 0, stream>>>(msk, biasb);

  // QKV mega-GEMM: 256^2 tiles, grid 16x24 = 384 blocks (384 % 8 == 0)
  gemm256<<<384, 512, 0, stream>>>(xb, encb, W4, Qb, Kb, Vtb,
                                   4096, 6144, 2048, cs_exp);

  attn_kernel<<<dim3(16, 16, 2), 256, 0, stream>>>(Qb, Kb, Vtb, biasb, Ob);

  // Final projection: 128x256 tiles, grid 32x8 = 256 blocks = one full round.
  gemm_proj<<<256, 512, 0, stream>>>(Ob, W4 + 3 * WELT, out, 4096, 2048, 2048);
}